// Round 8
// baseline (222.306 us; speedup 1.0000x reference)
//
#include <hip/hip_runtime.h>
#include <math.h>
#include <stdint.h>

// MultipleTopoTreeLoss = mean over 32 (sample,chunk) pairs of sum of squared
// Euclidean-MST edge lengths of 1024 standardized 3-D points.  Boruvka,
// one persistent kernel: 256 blocks = 32 samples x 8 parts, 1024 thr each,
// all co-resident (16 waves/block <= 32 waves/CU for any placement of 256
// blocks).  blockIdx&31 = sample -> all 8 parts of a sample on ONE XCD
// (blockIdx mod 8 == s mod 8), so barrier flags + winner tables stay L2-local.
//
// Round-5 post-mortem: 19us/round of which ~14 was overhead (fetch_add
// barrier chain, 1024-wide LDS clear+sweep, ~10 syncthreads in combine,
// per-round block reductions).  This round:
//   - flag barrier: block stores its own epoch (release), thread0 polls all
//     8 flags (acquire) -- no RMW contention, no reset (monotone epochs).
//   - tag logic kills all per-round clears: key = (15-rd)<<60 | d2<<20 |
//     min<<10 | max; tags DECREASE per round, so current-round keys always
//     win atomicMin over stale entries in both LDS and global tables.
//     Winner buffers pre-set to 0xFF by hipMemsetAsync (EMPTY = all-ones);
//     round 0 (tag 15 = EMPTY's tag) touches every slot, so no ambiguity.
//   - combine: 2-cycle break folded into the chase (next==prev -> root =
//     min), per-thread weight accumulation (block_sum once at the END),
//     ncomp==1 exit via __syncthreads_count.  7 syncs/round (was ~11).
// Dedupe/2-cycle correctness: symmetric distinct keys => total edge order =>
// hooking graph has only 2-cycles; both endpoints compute bitwise-identical
// d2 (negation-invariant squares); per-node argmin ties broken by smallest
// index, keeping per-comp key-monotonicity (passed absmax 0 in r2-r5).

#define NSAMP   32
#define NPTS    1024
#define SBLK    8
#define NPN     128
#define TPB     1024
#define MAXRD   11
#define EMPTY64 0xFFFFFFFFFFFFFFFFull

typedef unsigned long long u64;

__device__ __forceinline__ u64 aload64(const u64* p) {
  return __hip_atomic_load(p, __ATOMIC_RELAXED, __HIP_MEMORY_SCOPE_AGENT);
}

__device__ __forceinline__ void block_sum2(float& a, float& b, float* red) {
#pragma unroll
  for (int off = 32; off > 0; off >>= 1) {
    a += __shfl_xor(a, off, 64);
    b += __shfl_xor(b, off, 64);
  }
  __syncthreads();
  const int wid = threadIdx.x >> 6;
  if ((threadIdx.x & 63) == 0) { red[wid * 2] = a; red[wid * 2 + 1] = b; }
  __syncthreads();
  float ra = 0.f, rb = 0.f;
#pragma unroll
  for (int k = 0; k < 16; ++k) { ra += red[k * 2]; rb += red[k * 2 + 1]; }
  a = ra; b = rb;
}

__global__ __launch_bounds__(TPB) void topo_kernel(
    const float* __restrict__ r, u64* __restrict__ gw,
    int* __restrict__ flags, float* __restrict__ acc,
    int* __restrict__ done, float* __restrict__ out) {
  const int s    = blockIdx.x & 31;   // sample (same XCD for all its parts)
  const int part = blockIdx.x >> 5;   // 0..7
  const int tid  = threadIdx.x;

  __shared__ float4 P[NPTS];          // 16 KiB: xyz + comp-label bits in .w
  __shared__ u64 Wl[NPTS];            // 8 KiB: scan pre-reduce / combine copy
  __shared__ short parentL[NPTS];     // 2 KiB
  __shared__ float red[32];

  int* fl = flags + s * 32;           // 128 B per sample (own cacheline)
  u64* __restrict__ gws0 = gw + s * NPTS;
  u64* __restrict__ gws1 = gw + (NSAMP + s) * NPTS;

  // ---- standardize (redundant per block; bitwise-identical) ----
  const float* __restrict__ base = r + (size_t)s * (NPTS * 3);
  const float px = base[tid * 3 + 0];
  const float py = base[tid * 3 + 1];
  const float pz = base[tid * 3 + 2];
  float sx = px, sy = py, sz = pz, dm = 0.f;
  block_sum2(sx, sy, red); block_sum2(sz, dm, red);
  const float mx = sx * (1.f / NPTS), my = sy * (1.f / NPTS), mz = sz * (1.f / NPTS);
  const float ex = px - mx, ey = py - my, ez = pz - mz;
  float vx = ex * ex, vy = ey * ey, vz = ez * ez;
  dm = 0.f;
  block_sum2(vx, vy, red); block_sum2(vz, dm, red);
  const float ix = 1.f / (sqrtf(vx * (1.f / NPTS)) + 1e-8f);
  const float iy = 1.f / (sqrtf(vy * (1.f / NPTS)) + 1e-8f);
  const float iz = 1.f / (sqrtf(vz * (1.f / NPTS)) + 1e-8f);
  P[tid] = make_float4(ex * ix, ey * iy, ez * iz, __uint_as_float((unsigned)tid));
  Wl[tid] = EMPTY64;                  // one-time garbage guard
  __syncthreads();

  float total = 0.f;                  // per-THREAD edge-weight accumulation
  const int g  = tid >> 5, sl = tid & 31;
  const int n0 = part * NPN + g * 4;

  for (int rd = 0; rd < MAXRD; ++rd) {
    u64* __restrict__ gwc = (rd & 1) ? gws1 : gws0;
    const u64 tag = (u64)(15 - rd) << 60;   // decreasing: current wins min

    // ---- scan: 4 nodes x 32 candidates per thread ----
    float mex[4], mey[4], mez[4]; unsigned mc[4];
#pragma unroll
    for (int n = 0; n < 4; ++n) {
      const float4 p = P[n0 + n];
      mex[n] = p.x; mey[n] = p.y; mez[n] = p.z; mc[n] = __float_as_uint(p.w);
    }
    float bd[4]; int bj[4];
#pragma unroll
    for (int n = 0; n < 4; ++n) { bd[n] = INFINITY; bj[n] = n0 + n; }
#pragma unroll 8
    for (int jj = 0; jj < 32; ++jj) {
      const int j = sl + (jj << 5);
      const float4 q = P[j];          // lanes l, l+32 share addr: broadcast
      const unsigned qc = __float_as_uint(q.w);
#pragma unroll
      for (int n = 0; n < 4; ++n) {
        const float dx = mex[n] - q.x, dy = mey[n] - q.y, dz = mez[n] - q.z;
        float d2 = dx * dx + dy * dy + dz * dz;
        d2 = (qc == mc[n]) ? INFINITY : d2;
        if (d2 < bd[n]) { bd[n] = d2; bj[n] = j; }
      }
    }
#pragma unroll
    for (int off = 16; off > 0; off >>= 1) {    // reduce 32 sub-lanes
#pragma unroll
      for (int n = 0; n < 4; ++n) {
        const float od = __shfl_xor(bd[n], off, 64);
        const int   oj = __shfl_xor(bj[n], off, 64);
        if (od < bd[n] || (od == bd[n] && oj < bj[n])) { bd[n] = od; bj[n] = oj; }
      }
    }
    if (sl == 0) {                    // per-comp LDS pre-reduce (tagged keys)
#pragma unroll
      for (int n = 0; n < 4; ++n) {
        const int node = n0 + n, j = bj[n];
        const unsigned a = (unsigned)(node < j ? node : j);
        const unsigned b = (unsigned)(node < j ? j : node);
        const u64 key = tag | ((u64)__float_as_uint(bd[n]) << 20)
                      | (a << 10) | b;
        atomicMin(&Wl[mc[n]], key);
      }
    }
    __syncthreads();
    if (sl == 0) {                    // targeted flush (dup flushes are idempotent)
#pragma unroll
      for (int n = 0; n < 4; ++n) atomicMin(&gwc[mc[n]], Wl[mc[n]]);
    }

    // ---- flag barrier: monotone epochs, contention-free arrival ----
    __syncthreads();                  // drains each wave's vmcnt (flushes done)
    if (tid == 0) {
      __hip_atomic_store(&fl[part], rd + 1, __ATOMIC_RELEASE,
                         __HIP_MEMORY_SCOPE_AGENT);
      for (;;) {
        int mn = 0x7fffffff;
#pragma unroll
        for (int b2 = 0; b2 < SBLK; ++b2) {
          const int v = __hip_atomic_load(&fl[b2], __ATOMIC_ACQUIRE,
                                          __HIP_MEMORY_SCOPE_AGENT);
          mn = v < mn ? v : mn;
        }
        if (mn >= rd + 1) break;
        __builtin_amdgcn_s_sleep(1);
      }
    }
    __syncthreads();

    // ---- combine (redundant per block; deterministic) ----
    const u64 w = aload64(&gwc[tid]); // XCD-local L2
    Wl[tid] = w;
    __syncthreads();
    const unsigned curtag = (unsigned)(15 - rd);
    float wadd = 0.f;
    short par = (short)tid;
    if ((unsigned)(w >> 60) == curtag) {
      const int pmin = (int)((w >> 10) & 1023u);
      const int pmax = (int)(w & 1023u);
      const int cmin = (int)__float_as_uint(P[pmin].w);
      const int cmax = (int)__float_as_uint(P[pmax].w);
      const int c2 = (cmin == tid) ? cmax : cmin;
      par = (short)c2;
      const bool dup = (Wl[c2] == w); // same undirected edge <=> same key
      if (!dup || tid < c2)
        wadd = __uint_as_float((unsigned)((w >> 20) & 0xFFFFFFFFull));
    }
    parentL[tid] = par;
    __syncthreads();
    // chase to root with inline 2-cycle break (next==prev -> root = min)
    int c = (int)__float_as_uint(P[tid].w);
    {
      int prev = -1, p = c;
      for (int it = 0; it < 1024; ++it) {
        const int nx = parentL[p];
        if (nx == p) break;
        if (nx == prev) { p = p < prev ? p : prev; break; }
        prev = p; p = nx;
      }
      c = p;
    }
    total += wadd;
    const int cnt = __syncthreads_count(c == tid);  // = ncomp
    P[tid].w = __uint_as_float((unsigned)c);
    if (cnt == 1) break;              // uniform across blocks of the sample
    __syncthreads();                  // label writes visible to next scan
  }

  // ---- final reduction: one block_sum, part-0 publishes ----
  {
    float tt = total, dm2 = 0.f;
    block_sum2(tt, dm2, red);
    if (part == 0 && tid == 0) {
      atomicAdd(acc, tt);
      const int old = __hip_atomic_fetch_add(done, 1, __ATOMIC_ACQ_REL,
                                             __HIP_MEMORY_SCOPE_AGENT);
      if (old == NSAMP - 1) {
        const float t = __hip_atomic_load(acc, __ATOMIC_ACQUIRE,
                                          __HIP_MEMORY_SCOPE_AGENT);
        __hip_atomic_store(out, t * (1.f / NSAMP), __ATOMIC_RELAXED,
                           __HIP_MEMORY_SCOPE_SYSTEM);
      }
    }
  }
}

extern "C" void kernel_launch(void* const* d_in, const int* in_sizes, int n_in,
                              void* d_out, int out_size, void* d_ws, size_t ws_size,
                              hipStream_t stream) {
  const float* r = (const float*)d_in[0];
  float* out = (float*)d_out;
  (void)in_sizes; (void)n_in; (void)out_size; (void)ws_size;

  char* ws = (char*)d_ws;
  int*   flags = (int*)ws;                       // 32 x 128 B
  float* acc   = (float*)(ws + 4096);
  int*   done  = (int*)(ws + 4100);
  u64*   gw    = (u64*)(ws + 8192);              // 2 x 32 x 1024 x 8 B

  hipMemsetAsync(ws, 0, 4104, stream);                   // flags + acc + done
  hipMemsetAsync(ws + 8192, 0xFF, 2 * NSAMP * NPTS * sizeof(u64), stream);
  topo_kernel<<<dim3(NSAMP * SBLK), dim3(TPB), 0, stream>>>(
      r, gw, flags, acc, done, out);
}